// Round 9
// baseline (316.087 us; speedup 1.0000x reference)
//
#include <hip/hip_runtime.h>
#include <hip/hip_bf16.h>

#define B_ 4
#define T_ 2048
#define E_ 1024
#define H_ 16
#define DH_ 64
#define QSCALE_ 0.18033688f   // 0.125 * log2(e): QK^T comes out in log2 domain

typedef __attribute__((ext_vector_type(8))) short bf16x8;
typedef __attribute__((ext_vector_type(4))) short bf16x4;
typedef __attribute__((ext_vector_type(4))) float f32x4;
typedef unsigned int u32;

__device__ inline ushort f2bf(float f) {
    union { float f; unsigned u; } v; v.f = f;
    unsigned r = (v.u + 0x7fffu + ((v.u >> 16) & 1u)) >> 16;
    return (ushort)r;
}

// pack two f32 -> two bf16 (truncation) in one v_perm_b32: a->low, b->high
__device__ inline u32 pack2bf(float a, float b) {
    union { float f; u32 u; } ua, ub; ua.f = a; ub.f = b;
    return __builtin_amdgcn_perm(ub.u, ua.u, 0x07060302);
}

// K=16 bf16 MFMA: B-layout (k=quad*4+j) == 16x16 C-layout (row=quad*4+r),
// so an S^T accumulator feeds PV directly. Fallback: zero-padded K=32
// (slot k=quad*8+j, j<4 carries key base+quad*4+j in BOTH operands -> exact).
#if __has_builtin(__builtin_amdgcn_mfma_f32_16x16x16bf16_1k)
#define MFMA16(A, B, C) __builtin_amdgcn_mfma_f32_16x16x16bf16_1k(A, B, C, 0, 0, 0)
#else
__device__ inline f32x4 mfma16_emul(bf16x4 a, bf16x4 b, f32x4 c) {
    bf16x8 a8 = {a[0], a[1], a[2], a[3], 0, 0, 0, 0};
    bf16x8 b8 = {b[0], b[1], b[2], b[3], 0, 0, 0, 0};
    return __builtin_amdgcn_mfma_f32_16x16x32_bf16(a8, b8, c, 0, 0, 0);
}
#define MFMA16(A, B, C) mfma16_emul(A, B, C)
#endif

__device__ inline void gload16(const ushort* g, ushort* l) {
    __builtin_amdgcn_global_load_lds((const __attribute__((address_space(1))) u32*)g,
                                     (__attribute__((address_space(3))) u32*)l, 16, 0, 0);
}

// ---------------- fused f32 -> bf16 convert ----------------
__global__ void cvt_all(const float* __restrict__ x, const float* __restrict__ wq,
                        const float* __restrict__ wp,
                        ushort* __restrict__ xo, ushort* __restrict__ wqo, ushort* __restrict__ wpo)
{
    const int NX = B_ * T_ * E_ / 4;
    const int NW = 3 * E_ * E_ / 4;
    int i = blockIdx.x * 256 + threadIdx.x;
    const float* s; ushort* d; int off;
    if (i < NX)            { s = x;  d = xo;  off = i; }
    else if (i < NX + NW)  { s = wq; d = wqo; off = i - NX; }
    else                   { s = wp; d = wpo; off = i - NX - NW; }
    float4 f = ((const float4*)s)[off];
    ushort4 u;
    u.x = f2bf(f.x); u.y = f2bf(f.y); u.z = f2bf(f.z); u.w = f2bf(f.w);
    ((ushort4*)d)[off] = u;
}

// ---------------- QKV GEMM: 128x128 tile, BK=32, global_load_lds ----------------
__global__ __launch_bounds__(256) void gemm_qkv(
    const ushort* __restrict__ Xb, const ushort* __restrict__ Wb,
    const float* __restrict__ bias,
    ushort* __restrict__ Q, ushort* __restrict__ K, ushort* __restrict__ Vt)
{
    __shared__ ushort As[128 * 32];
    __shared__ ushort Bs[128 * 32];
    const int m0 = blockIdx.x * 128;
    const int n0 = blockIdx.y * 128;
    const int kind = n0 >> 10;           // 0=Q 1=K 2=V (block-uniform)
    const int tid  = threadIdx.x;
    const int wave = tid >> 6, lane = tid & 63;
    const int lrow = lane & 15, quad = lane >> 4;
    const int srow = lane >> 2, scol = (lane & 3) * 8;

    const ushort* gA0 = Xb + (size_t)(m0 + wave * 32 + srow) * 1024 + scol;
    const ushort* gA1 = gA0 + (size_t)16 * 1024;
    const ushort* gB0 = Wb + (size_t)(n0 + wave * 32 + srow) * 1024 + scol;
    const ushort* gB1 = gB0 + (size_t)16 * 1024;
    ushort* lA0 = &As[(wave * 32) * 32];
    ushort* lA1 = &As[(wave * 32 + 16) * 32];
    ushort* lB0 = &Bs[(wave * 32) * 32];
    ushort* lB1 = &Bs[(wave * 32 + 16) * 32];

    const int mw = (wave >> 1) * 64, nw = (wave & 1) * 64;

    f32x4 acc[4][4];
#pragma unroll
    for (int i = 0; i < 4; i++)
#pragma unroll
        for (int j = 0; j < 4; j++) acc[i][j] = f32x4{0.f, 0.f, 0.f, 0.f};

    const int b = m0 >> 11;   // batch (block never straddles a 2048 boundary)

    if (kind != 2) {
        for (int k0 = 0; k0 < 1024; k0 += 32) {
            __syncthreads();
            gload16(gA0 + k0, lA0);
            gload16(gA1 + k0, lA1);
            gload16(gB0 + k0, lB0);
            gload16(gB1 + k0, lB1);
            __syncthreads();
            bf16x8 a[4], bfr[4];
#pragma unroll
            for (int i = 0; i < 4; i++)
                a[i] = *(const bf16x8*)&As[(mw + i * 16 + lrow) * 32 + quad * 8];
#pragma unroll
            for (int j = 0; j < 4; j++)
                bfr[j] = *(const bf16x8*)&Bs[(nw + j * 16 + lrow) * 32 + quad * 8];
#pragma unroll
            for (int i = 0; i < 4; i++)
#pragma unroll
                for (int j = 0; j < 4; j++)
                    acc[i][j] = __builtin_amdgcn_mfma_f32_16x16x32_bf16(bfr[j], a[i], acc[i][j], 0, 0, 0);
        }
        ushort* dst = (kind == 0) ? Q : K;
        const float scale = (kind == 0) ? QSCALE_ : 1.f;
#pragma unroll
        for (int j = 0; j < 4; j++) {
            int nq = (n0 & 1023) + nw + j * 16 + quad * 4;
            int h = nq >> 6, d = nq & 63;
            float4 bv = *(const float4*)&bias[n0 + nw + j * 16 + quad * 4];
            size_t bh = (size_t)(b * H_ + h);
#pragma unroll
            for (int i = 0; i < 4; i++) {
                int t = (m0 + mw + i * 16 + lrow) & 2047;   // batch-local!
                ushort4 o;
                o.x = f2bf((acc[i][j][0] + bv.x) * scale);
                o.y = f2bf((acc[i][j][1] + bv.y) * scale);
                o.z = f2bf((acc[i][j][2] + bv.z) * scale);
                o.w = f2bf((acc[i][j][3] + bv.w) * scale);
                *(ushort4*)&dst[(bh * T_ + t) * DH_ + d] = o;
            }
        }
    } else {
        for (int k0 = 0; k0 < 1024; k0 += 32) {
            __syncthreads();
            gload16(gA0 + k0, lA0);
            gload16(gA1 + k0, lA1);
            gload16(gB0 + k0, lB0);
            gload16(gB1 + k0, lB1);
            __syncthreads();
            bf16x8 a[4], bfr[4];
#pragma unroll
            for (int i = 0; i < 4; i++)
                a[i] = *(const bf16x8*)&As[(mw + i * 16 + lrow) * 32 + quad * 8];
#pragma unroll
            for (int j = 0; j < 4; j++)
                bfr[j] = *(const bf16x8*)&Bs[(nw + j * 16 + lrow) * 32 + quad * 8];
#pragma unroll
            for (int i = 0; i < 4; i++)
#pragma unroll
                for (int j = 0; j < 4; j++)
                    acc[i][j] = __builtin_amdgcn_mfma_f32_16x16x32_bf16(a[i], bfr[j], acc[i][j], 0, 0, 0);
        }
#pragma unroll
        for (int j = 0; j < 4; j++) {
            int nv = (n0 & 1023) + nw + j * 16 + lrow;
            int h = nv >> 6, d = nv & 63;
            float bv = bias[n0 + nw + j * 16 + lrow];
            size_t bh = (size_t)(b * H_ + h);
#pragma unroll
            for (int i = 0; i < 4; i++) {
                int t = (m0 + mw + i * 16 + quad * 4) & 2047;   // batch-local!
                ushort4 o;
                o.x = f2bf(acc[i][j][0] + bv);
                o.y = f2bf(acc[i][j][1] + bv);
                o.z = f2bf(acc[i][j][2] + bv);
                o.w = f2bf(acc[i][j][3] + bv);
                *(ushort4*)&Vt[(bh * DH_ + d) * T_ + t] = o;
            }
        }
    }
}

// ---------------- Flash attention: paired q-tiles, P kept in registers ----------------
// Block x: q-tiles (15-x, x) => (qtA+1)+(qtB+1) = 17 128-key rounds, constant.
// S computed transposed via mfma(K, Q^T); its C-layout feeds PV directly as the
// B-operand of K=16 MFMA (A = V^T), accumulating O^T. No P LDS round-trip.
#define LDK_ 76     // Ks[key][dh], 2-way max bank aliasing on b128 frag reads
#define LDV_ 136    // Vt[d][key],  2-way max on b64 frag reads

__global__ __launch_bounds__(256) void flash_attn(
    const ushort* __restrict__ Q, const ushort* __restrict__ K,
    const ushort* __restrict__ Vg,   // [bh][DH][T]
    ushort* __restrict__ O)
{
    __shared__ ushort Ks[128 * LDK_];   // also Q staging (128x64 fits exactly)
    __shared__ ushort Vt[64 * LDV_];

    const int qtA = 15 - blockIdx.x;
    const int qtB = blockIdx.x;
    const int bh = blockIdx.y;
    const int tid  = threadIdx.x;
    const int wave = tid >> 6, lane = tid & 63;
    const int lrow = lane & 15, quad = lane >> 4;

    const ushort* Qbh = Q  + (size_t)bh * T_ * DH_;
    const ushort* Kbh = K  + (size_t)bh * T_ * DH_;
    const ushort* Vbh = Vg + (size_t)bh * DH_ * T_;
    const int b_ = bh >> 4, h_ = bh & 15;

    // staging coords
    const int kq = tid >> 1, kc = (tid & 1) * 32;   // K: 128 rows x 64, 32B/thread... 64B/thread (4 int4)
    const int vd = tid >> 2, vc = (tid & 3) * 32;   // V: 64 rows x 128

    auto stageQ = [&](int qt, bf16x8 qa[2][2]) {
        const ushort* src = &Qbh[(size_t)(qt * 128 + kq) * DH_ + kc];
#pragma unroll
        for (int i = 0; i < 4; i++)
            *(int4*)&Ks[kq * LDK_ + kc + 8 * i] = *(const int4*)&src[8 * i];
        __syncthreads();
#pragma unroll
        for (int s = 0; s < 2; s++)
#pragma unroll
            for (int h = 0; h < 2; h++)
                qa[s][h] = *(const bf16x8*)&Ks[(s * 64 + wave * 16 + lrow) * LDK_ + h * 32 + quad * 8];
    };

    bf16x8 qaA[2][2], qaB[2][2];
    stageQ(qtA, qaA);
    __syncthreads();
    stageQ(qtB, qaB);
    // run()'s first barrier protects qaB reads before Ks is overwritten

    auto run = [&](const bf16x8 (&qa)[2][2], int qt) {
        const int rounds = qt + 1;            // 128 keys per round
        const int lastTile = 2 * qt + 1;      // 64-key tile index of the diagonal for strip1

        int4 kr[4], vr[4];
#pragma unroll
        for (int i = 0; i < 4; i++) {
            kr[i] = *(const int4*)&Kbh[(size_t)kq * DH_ + kc + 8 * i];
            vr[i] = *(const int4*)&Vbh[(size_t)vd * T_ + vc + 8 * i];
        }

        float ls[2] = {0.f, 0.f};
        f32x4 accOT[2][4];
#pragma unroll
        for (int s = 0; s < 2; s++)
#pragma unroll
            for (int j = 0; j < 4; j++) accOT[s][j] = f32x4{0.f, 0.f, 0.f, 0.f};

        for (int r2 = 0; r2 < rounds; ++r2) {
            __syncthreads();
#pragma unroll
            for (int i = 0; i < 4; i++) {
                *(int4*)&Ks[kq * LDK_ + kc + 8 * i] = kr[i];
                *(int4*)&Vt[vd * LDV_ + vc + 8 * i] = vr[i];
            }
            __syncthreads();
            if (r2 + 1 < rounds) {
#pragma unroll
                for (int i = 0; i < 4; i++) {
                    kr[i] = *(const int4*)&Kbh[(size_t)((r2 + 1) * 128 + kq) * DH_ + kc + 8 * i];
                    vr[i] = *(const int4*)&Vbh[(size_t)vd * T_ + (r2 + 1) * 128 + vc + 8 * i];
                }
            }

#pragma unroll
            for (int h = 0; h < 2; ++h) {
                const int tile = 2 * r2 + h;
                const bool act0 = (tile != lastTile);   // strip0 fully masked on final tile

                bf16x8 kb0[4], kb1[4];
#pragma unroll
                for (int j = 0; j < 4; j++) {
                    kb0[j] = *(const bf16x8*)&Ks[(h * 64 + j * 16 + lrow) * LDK_ + quad * 8];
                    kb1[j] = *(const bf16x8*)&Ks[(h * 64 + j * 16 + lrow) * LDK_ + 32 + quad * 8];
                }

                f32x4 st[2][4];
#pragma unroll
                for (int s = 0; s < 2; s++) {
                    if (s == 0 && !act0) continue;
#pragma unroll
                    for (int j = 0; j < 4; j++) {
                        f32x4 sj = f32x4{0.f, 0.f, 0.f, 0.f};
                        sj = __builtin_amdgcn_mfma_f32_16x16x32_bf16(kb0[j], qa[s][0], sj, 0, 0, 0);
                        sj = __builtin_amdgcn_mfma_f32_16x16x32_bf16(kb1[j], qa[s][1], sj, 0, 0, 0);
                        st[s][j] = sj;
                    }
                    if (tile == 2 * qt + s) {           // diagonal tile for this strip
                        const int qrow = qt * 128 + s * 64 + wave * 16 + lrow;
                        const int keyb = tile * 64 + quad * 4;
#pragma unroll
                        for (int j = 0; j < 4; j++)
#pragma unroll
                            for (int r = 0; r < 4; r++)
                                if (keyb + j * 16 + r > qrow) st[s][j][r] = -1e30f;
                    }
                    float lp = 0.f;
#pragma unroll
                    for (int j = 0; j < 4; j++)
#pragma unroll
                        for (int r = 0; r < 4; r++) {
                            float p = __builtin_amdgcn_exp2f(st[s][j][r]);
                            st[s][j][r] = p;
                            lp += p;
                        }
                    ls[s] += lp;
                }

                // PV: A = V^T frags (shared across strips), B = packed st (in regs)
#pragma unroll
                for (int kg = 0; kg < 4; ++kg) {
                    bf16x4 va[4];
#pragma unroll
                    for (int jd = 0; jd < 4; jd++)
                        va[jd] = *(const bf16x4*)&Vt[(jd * 16 + lrow) * LDV_ + h * 64 + kg * 16 + quad * 4];
#pragma unroll
                    for (int s = 0; s < 2; s++) {
                        if (s == 0 && !act0) continue;
                        union { u32 u[2]; bf16x4 v; } pu;
                        pu.u[0] = pack2bf(st[s][kg][0], st[s][kg][1]);
                        pu.u[1] = pack2bf(st[s][kg][2], st[s][kg][3]);
                        bf16x4 pb = pu.v;
#pragma unroll
                        for (int jd = 0; jd < 4; jd++)
                            accOT[s][jd] = MFMA16(va[jd], pb, accOT[s][jd]);
                    }
                }
            }
        }

        // l per lane covers column q=lrow; reduce over quads
#pragma unroll
        for (int s = 0; s < 2; s++) {
            ls[s] += __shfl_xor(ls[s], 16, 64);
            ls[s] += __shfl_xor(ls[s], 32, 64);
        }
        // epilogue: O^T layout -> lane owns one t (=lrow row), d = jd*16+quad*4+r
#pragma unroll
        for (int s = 0; s < 2; s++) {
            float inv = 1.f / ls[s];
            int t = qt * 128 + s * 64 + wave * 16 + lrow;
            ushort* orow = &O[((size_t)(b_ * T_ + t)) * E_ + h_ * DH_ + quad * 4];
#pragma unroll
            for (int jd = 0; jd < 4; jd++) {
                ushort4 o;
                o.x = f2bf(accOT[s][jd][0] * inv);
                o.y = f2bf(accOT[s][jd][1] * inv);
                o.z = f2bf(accOT[s][jd][2] * inv);
                o.w = f2bf(accOT[s][jd][3] * inv);
                *(ushort4*)&orow[jd * 16] = o;
            }
        }
    };

    run(qaA, qtA);
    run(qaB, qtB);
}

// ---------------- proj GEMM: 128x128 tile, C^T orientation for float4 stores ----------------
__global__ __launch_bounds__(256) void gemm_proj(
    const ushort* __restrict__ Ob, const ushort* __restrict__ Wb,
    const float* __restrict__ bias, float* __restrict__ out)
{
    __shared__ ushort As[128 * 32];
    __shared__ ushort Bs[128 * 32];
    const int m0 = blockIdx.x * 128;
    const int n0 = blockIdx.y * 128;
    const int tid  = threadIdx.x;
    const int wave = tid >> 6, lane = tid & 63;
    const int lrow = lane & 15, quad = lane >> 4;
    const int srow = lane >> 2, scol = (lane & 3) * 8;

    const ushort* gA0 = Ob + (size_t)(m0 + wave * 32 + srow) * 1024 + scol;
    const ushort* gA1 = gA0 + (size_t)16 * 1024;
    const ushort* gB0 = Wb + (size_t)(n0 + wave * 32 + srow) * 1024 + scol;
    const ushort* gB1 = gB0 + (size_t)16 * 1024;
    ushort* lA0 = &As[(wave * 32) * 32];
    ushort* lA1 = &As[(wave * 32 + 16) * 32];
    ushort* lB0 = &Bs[(wave * 32) * 32];
    ushort* lB1 = &Bs[(wave * 32 + 16) * 32];

    const int mw = (wave >> 1) * 64, nw = (wave & 1) * 64;

    f32x4 acc[4][4];
#pragma unroll
    for (int i = 0; i < 4; i++)
#pragma unroll
        for (int j = 0; j < 4; j++) acc[i][j] = f32x4{0.f, 0.f, 0.f, 0.f};

    for (int k0 = 0; k0 < 1024; k0 += 32) {
        __syncthreads();
        gload16(gA0 + k0, lA0);
        gload16(gA1 + k0, lA1);
        gload16(gB0 + k0, lB0);
        gload16(gB1 + k0, lB1);
        __syncthreads();
        bf16x8 a[4], bfr[4];
#pragma unroll
        for (int i = 0; i < 4; i++)
            a[i] = *(const bf16x8*)&As[(mw + i * 16 + lrow) * 32 + quad * 8];
#pragma unroll
        for (int j = 0; j < 4; j++)
            bfr[j] = *(const bf16x8*)&Bs[(nw + j * 16 + lrow) * 32 + quad * 8];
#pragma unroll
        for (int i = 0; i < 4; i++)
#pragma unroll
            for (int j = 0; j < 4; j++)
                acc[i][j] = __builtin_amdgcn_mfma_f32_16x16x32_bf16(bfr[j], a[i], acc[i][j], 0, 0, 0);
    }

#pragma unroll
    for (int j = 0; j < 4; j++) {
        int n = n0 + nw + j * 16 + quad * 4;
        float4 bv = *(const float4*)&bias[n];
#pragma unroll
        for (int i = 0; i < 4; i++) {
            int m = m0 + mw + i * 16 + lrow;
            float4 o;
            o.x = acc[i][j][0] + bv.x;
            o.y = acc[i][j][1] + bv.y;
            o.z = acc[i][j][2] + bv.z;
            o.w = acc[i][j][3] + bv.w;
            *(float4*)&out[(size_t)m * 1024 + n] = o;
        }
    }
}

extern "C" void kernel_launch(void* const* d_in, const int* in_sizes, int n_in,
                              void* d_out, int out_size, void* d_ws, size_t ws_size,
                              hipStream_t stream) {
    const float* x      = (const float*)d_in[0];
    const float* w_qkv  = (const float*)d_in[1];
    const float* b_qkv  = (const float*)d_in[2];
    const float* w_proj = (const float*)d_in[3];
    const float* b_proj = (const float*)d_in[4];
    float* out = (float*)d_out;

    char* ws = (char*)d_ws;
    ushort* Xb     = (ushort*)ws; ws += (size_t)B_ * T_ * E_ * 2;
    ushort* Wqkvb  = (ushort*)ws; ws += (size_t)3 * E_ * E_ * 2;
    ushort* Wprojb = (ushort*)ws; ws += (size_t)E_ * E_ * 2;
    ushort* Qb     = (ushort*)ws; ws += (size_t)B_ * H_ * T_ * DH_ * 2;
    ushort* Kb     = (ushort*)ws; ws += (size_t)B_ * H_ * T_ * DH_ * 2;
    ushort* Vtb    = (ushort*)ws; ws += (size_t)B_ * H_ * T_ * DH_ * 2;
    ushort* Ob     = (ushort*)ws; ws += (size_t)B_ * T_ * E_ * 2;

    int ntot = (B_ * T_ * E_ + 3 * E_ * E_ + E_ * E_) / 4;
    cvt_all<<<ntot / 256, 256, 0, stream>>>(x, w_qkv, w_proj, Xb, Wqkvb, Wprojb);

    gemm_qkv<<<dim3(64, 24), 256, 0, stream>>>(Xb, Wqkvb, b_qkv, Qb, Kb, Vtb);
    flash_attn<<<dim3(8, 64), 256, 0, stream>>>(Qb, Kb, Vtb, Ob);
    gemm_proj<<<dim3(64, 8), 256, 0, stream>>>(Ob, Wprojb, b_proj, out);
}

// Round 10
// 264.399 us; speedup vs baseline: 1.1955x; 1.1955x over previous
//
#include <hip/hip_runtime.h>
#include <hip/hip_bf16.h>

#define B_ 4
#define T_ 2048
#define E_ 1024
#define H_ 16
#define DH_ 64
#define QSCALE_ 0.18033688f   // 0.125 * log2(e): QK^T comes out in log2 domain

typedef __attribute__((ext_vector_type(8))) short bf16x8;
typedef __attribute__((ext_vector_type(4))) float f32x4;
typedef unsigned int u32;

__device__ inline ushort f2bf(float f) {
    union { float f; unsigned u; } v; v.f = f;
    unsigned r = (v.u + 0x7fffu + ((v.u >> 16) & 1u)) >> 16;
    return (ushort)r;
}

// pack two f32 -> two bf16 (truncation) in one v_perm_b32: a->low, b->high
__device__ inline u32 pack2bf(float a, float b) {
    union { float f; u32 u; } ua, ub; ua.f = a; ub.f = b;
    return __builtin_amdgcn_perm(ub.u, ua.u, 0x07060302);
}

__device__ inline void gload16(const ushort* g, ushort* l) {
    __builtin_amdgcn_global_load_lds((const __attribute__((address_space(1))) u32*)g,
                                     (__attribute__((address_space(3))) u32*)l, 16, 0, 0);
}

// ---------------- fused f32 -> bf16 convert ----------------
__global__ void cvt_all(const float* __restrict__ x, const float* __restrict__ wq,
                        const float* __restrict__ wp,
                        ushort* __restrict__ xo, ushort* __restrict__ wqo, ushort* __restrict__ wpo)
{
    const int NX = B_ * T_ * E_ / 4;
    const int NW = 3 * E_ * E_ / 4;
    int i = blockIdx.x * 256 + threadIdx.x;
    const float* s; ushort* d; int off;
    if (i < NX)            { s = x;  d = xo;  off = i; }
    else if (i < NX + NW)  { s = wq; d = wqo; off = i - NX; }
    else                   { s = wp; d = wpo; off = i - NX - NW; }
    float4 f = ((const float4*)s)[off];
    ushort4 u;
    u.x = f2bf(f.x); u.y = f2bf(f.y); u.z = f2bf(f.z); u.w = f2bf(f.w);
    ((ushort4*)d)[off] = u;
}

// ---------------- QKV GEMM: 128x128 tile, BK=64 (halved barrier rounds) ----------------
__global__ __launch_bounds__(256) void gemm_qkv(
    const ushort* __restrict__ Xb, const ushort* __restrict__ Wb,
    const float* __restrict__ bias,
    ushort* __restrict__ Q, ushort* __restrict__ K, ushort* __restrict__ Vt)
{
    __shared__ ushort As[128 * 64];
    __shared__ ushort Bs[128 * 64];
    const int m0 = blockIdx.x * 128;
    const int n0 = blockIdx.y * 128;
    const int kind = n0 >> 10;           // 0=Q 1=K 2=V (block-uniform)
    const int tid  = threadIdx.x;
    const int wave = tid >> 6, lane = tid & 63;
    const int lrow = lane & 15, quad = lane >> 4;
    const int srow8 = lane >> 3, scol8 = (lane & 7) * 8;   // 8 rows x 64 cols per wave-issue

    const ushort* gA = Xb + (size_t)(m0 + wave * 8 + srow8) * 1024 + scol8;
    const ushort* gB = Wb + (size_t)(n0 + wave * 8 + srow8) * 1024 + scol8;

    const int mw = (wave >> 1) * 64, nw = (wave & 1) * 64;

    f32x4 acc[4][4];
#pragma unroll
    for (int i = 0; i < 4; i++)
#pragma unroll
        for (int j = 0; j < 4; j++) acc[i][j] = f32x4{0.f, 0.f, 0.f, 0.f};

    const int b = m0 >> 11;   // batch (block never straddles a 2048 boundary)
    const bool ct = (kind != 2);

    for (int k0 = 0; k0 < 1024; k0 += 64) {
        __syncthreads();
#pragma unroll
        for (int g = 0; g < 4; g++) {
            gload16(gA + (size_t)g * 32 * 1024 + k0, &As[(g * 32 + wave * 8) * 64]);
            gload16(gB + (size_t)g * 32 * 1024 + k0, &Bs[(g * 32 + wave * 8) * 64]);
        }
        __syncthreads();
#pragma unroll
        for (int ks = 0; ks < 2; ks++) {
            bf16x8 a[4], bfr[4];
#pragma unroll
            for (int i = 0; i < 4; i++)
                a[i] = *(const bf16x8*)&As[(mw + i * 16 + lrow) * 64 + ks * 32 + quad * 8];
#pragma unroll
            for (int j = 0; j < 4; j++)
                bfr[j] = *(const bf16x8*)&Bs[(nw + j * 16 + lrow) * 64 + ks * 32 + quad * 8];
            if (ct) {
#pragma unroll
                for (int i = 0; i < 4; i++)
#pragma unroll
                    for (int j = 0; j < 4; j++)
                        acc[i][j] = __builtin_amdgcn_mfma_f32_16x16x32_bf16(bfr[j], a[i], acc[i][j], 0, 0, 0);
            } else {
#pragma unroll
                for (int i = 0; i < 4; i++)
#pragma unroll
                    for (int j = 0; j < 4; j++)
                        acc[i][j] = __builtin_amdgcn_mfma_f32_16x16x32_bf16(a[i], bfr[j], acc[i][j], 0, 0, 0);
            }
        }
    }

    if (ct) {
        // C^T: lane holds m = mw+i*16+lrow, n = nw+j*16+quad*4+r -> ushort4 along d
        ushort* dst = (kind == 0) ? Q : K;
        const float scale = (kind == 0) ? QSCALE_ : 1.f;
#pragma unroll
        for (int j = 0; j < 4; j++) {
            int nq = (n0 & 1023) + nw + j * 16 + quad * 4;
            int h = nq >> 6, d = nq & 63;
            float4 bv = *(const float4*)&bias[n0 + nw + j * 16 + quad * 4];
            size_t bh = (size_t)(b * H_ + h);
#pragma unroll
            for (int i = 0; i < 4; i++) {
                int t = (m0 + mw + i * 16 + lrow) & 2047;   // batch-local!
                ushort4 o;
                o.x = f2bf((acc[i][j][0] + bv.x) * scale);
                o.y = f2bf((acc[i][j][1] + bv.y) * scale);
                o.z = f2bf((acc[i][j][2] + bv.z) * scale);
                o.w = f2bf((acc[i][j][3] + bv.w) * scale);
                *(ushort4*)&dst[(bh * T_ + t) * DH_ + d] = o;
            }
        }
    } else {
        // normal: lane holds n = nw+j*16+lrow, t = mw+i*16+quad*4+r -> ushort4 along t
#pragma unroll
        for (int j = 0; j < 4; j++) {
            int nv = (n0 & 1023) + nw + j * 16 + lrow;
            int h = nv >> 6, d = nv & 63;
            float bv = bias[n0 + nw + j * 16 + lrow];
            size_t bh = (size_t)(b * H_ + h);
#pragma unroll
            for (int i = 0; i < 4; i++) {
                int t = (m0 + mw + i * 16 + quad * 4) & 2047;   // batch-local!
                ushort4 o;
                o.x = f2bf(acc[i][j][0] + bv);
                o.y = f2bf(acc[i][j][1] + bv);
                o.z = f2bf(acc[i][j][2] + bv);
                o.w = f2bf(acc[i][j][3] + bv);
                *(ushort4*)&Vt[(bh * DH_ + d) * T_ + t] = o;
            }
        }
    }
}

// ---------------- Flash attention: paired q-tiles (R8-proven version) ----------------
#define LDT_ 76

__global__ __launch_bounds__(256) void flash_attn(
    const ushort* __restrict__ Q, const ushort* __restrict__ K,
    const ushort* __restrict__ Vg,   // [bh][DH][T]
    ushort* __restrict__ O)
{
    __shared__ ushort Ks[64 * LDT_];
    __shared__ ushort Vt[64 * LDT_];
    __shared__ ushort Ps[128 * LDT_];   // doubles as Q staging

    const int qtA = 15 - blockIdx.x;     // long tile
    const int qtB = blockIdx.x;          // short tile
    const int bh = blockIdx.y;
    const int tid  = threadIdx.x;
    const int wave = tid >> 6, lane = tid & 63;
    const int lrow = lane & 15, quad = lane >> 4;
    const int sr = tid >> 2, sc = (tid & 3) * 16;   // K/V staging coords

    const ushort* Qbh = Q  + (size_t)bh * T_ * DH_;
    const ushort* Kbh = K  + (size_t)bh * T_ * DH_;
    const ushort* Vbh = Vg + (size_t)bh * DH_ * T_;
    const int b_ = bh >> 4, h_ = bh & 15;

    auto stageQ = [&](int qt, bf16x8 qa[2][2]) {
        int qr = tid >> 1, qc = (tid & 1) * 32;
        const ushort* src = &Qbh[(size_t)(qt * 128 + qr) * DH_ + qc];
#pragma unroll
        for (int i = 0; i < 4; i++)
            *(int4*)&Ps[qr * LDT_ + qc + 8 * i] = *(const int4*)&src[8 * i];
        __syncthreads();
#pragma unroll
        for (int s = 0; s < 2; s++)
#pragma unroll
            for (int h = 0; h < 2; h++)
                qa[s][h] = *(const bf16x8*)&Ps[(s * 64 + wave * 16 + lrow) * LDT_ + h * 32 + quad * 8];
    };

    bf16x8 qaA[2][2], qaB[2][2];
    stageQ(qtA, qaA);
    __syncthreads();
    stageQ(qtB, qaB);

    auto run = [&](const bf16x8 (&qa)[2][2], int qt) {
        const int lastkt = 2 * qt + 1;

        int4 kr0 = *(const int4*)&Kbh[(size_t)sr * DH_ + sc];
        int4 kr1 = *(const int4*)&Kbh[(size_t)sr * DH_ + sc + 8];
        int4 vr0 = *(const int4*)&Vbh[(size_t)sr * T_ + sc];
        int4 vr1 = *(const int4*)&Vbh[(size_t)sr * T_ + sc + 8];

        float ls[2] = {0.f, 0.f};
        f32x4 accO[2][4];
#pragma unroll
        for (int s = 0; s < 2; s++)
#pragma unroll
            for (int j = 0; j < 4; j++) accO[s][j] = f32x4{0.f, 0.f, 0.f, 0.f};

        for (int kt = 0; kt <= lastkt; ++kt) {
            __syncthreads();
            *(int4*)&Ks[sr * LDT_ + sc]     = kr0;
            *(int4*)&Ks[sr * LDT_ + sc + 8] = kr1;
            *(int4*)&Vt[sr * LDT_ + sc]     = vr0;
            *(int4*)&Vt[sr * LDT_ + sc + 8] = vr1;
            __syncthreads();
            if (kt < lastkt) {
                kr0 = *(const int4*)&Kbh[(size_t)((kt + 1) * 64 + sr) * DH_ + sc];
                kr1 = *(const int4*)&Kbh[(size_t)((kt + 1) * 64 + sr) * DH_ + sc + 8];
                vr0 = *(const int4*)&Vbh[(size_t)sr * T_ + (kt + 1) * 64 + sc];
                vr1 = *(const int4*)&Vbh[(size_t)sr * T_ + (kt + 1) * 64 + sc + 8];
            }

            bf16x8 kb0[4], kb1[4];
#pragma unroll
            for (int j = 0; j < 4; j++) {
                kb0[j] = *(const bf16x8*)&Ks[(j * 16 + lrow) * LDT_ + quad * 8];
                kb1[j] = *(const bf16x8*)&Ks[(j * 16 + lrow) * LDT_ + 32 + quad * 8];
            }

            const bool do0 = (kt != lastkt);
#pragma unroll
            for (int s = 0; s < 2; s++) {
                if (s == 0 && !do0) continue;
                f32x4 st[4];
#pragma unroll
                for (int j = 0; j < 4; j++) {
                    f32x4 sj = f32x4{0.f, 0.f, 0.f, 0.f};
                    sj = __builtin_amdgcn_mfma_f32_16x16x32_bf16(kb0[j], qa[s][0], sj, 0, 0, 0);
                    sj = __builtin_amdgcn_mfma_f32_16x16x32_bf16(kb1[j], qa[s][1], sj, 0, 0, 0);
                    st[j] = sj;
                }
                if (kt == 2 * qt + s) {
                    const int qrow = qt * 128 + s * 64 + wave * 16 + lrow;
                    const int keyb = kt * 64 + quad * 4;
#pragma unroll
                    for (int j = 0; j < 4; j++)
#pragma unroll
                        for (int r = 0; r < 4; r++)
                            if (keyb + j * 16 + r > qrow) st[j][r] = -1e30f;
                }
                float lp = 0.f;
#pragma unroll
                for (int j = 0; j < 4; j++)
#pragma unroll
                    for (int r = 0; r < 4; r++) {
                        float p = __builtin_amdgcn_exp2f(st[j][r]);
                        st[j][r] = p;
                        lp += p;
                    }
                ls[s] += lp;
                ushort* prow = &Ps[(s * 64 + wave * 16 + lrow) * LDT_ + quad * 4];
#pragma unroll
                for (int j = 0; j < 4; j++) {
                    *(u32*)&prow[j * 16]     = pack2bf(st[j][0], st[j][1]);
                    *(u32*)&prow[j * 16 + 2] = pack2bf(st[j][2], st[j][3]);
                }
            }

            bf16x8 vb0[4], vb1[4];
#pragma unroll
            for (int j = 0; j < 4; j++) {
                vb0[j] = *(const bf16x8*)&Vt[(j * 16 + lrow) * LDT_ + quad * 8];
                vb1[j] = *(const bf16x8*)&Vt[(j * 16 + lrow) * LDT_ + 32 + quad * 8];
            }
#pragma unroll
            for (int s = 0; s < 2; s++) {
                if (s == 0 && !do0) continue;
                bf16x8 pa0 = *(const bf16x8*)&Ps[(s * 64 + wave * 16 + lrow) * LDT_ + quad * 8];
                bf16x8 pa1 = *(const bf16x8*)&Ps[(s * 64 + wave * 16 + lrow) * LDT_ + 32 + quad * 8];
#pragma unroll
                for (int jd = 0; jd < 4; jd++) {
                    accO[s][jd] = __builtin_amdgcn_mfma_f32_16x16x32_bf16(pa0, vb0[jd], accO[s][jd], 0, 0, 0);
                    accO[s][jd] = __builtin_amdgcn_mfma_f32_16x16x32_bf16(pa1, vb1[jd], accO[s][jd], 0, 0, 0);
                }
            }
        }

#pragma unroll
        for (int s = 0; s < 2; s++) {
            ls[s] += __shfl_xor(ls[s], 16, 64);
            ls[s] += __shfl_xor(ls[s], 32, 64);
        }
#pragma unroll
        for (int s = 0; s < 2; s++) {
#pragma unroll
            for (int r = 0; r < 4; r++) {
                float lv = __shfl(ls[s], quad * 4 + r, 64);
                float inv = 1.f / lv;
                int t = qt * 128 + s * 64 + wave * 16 + quad * 4 + r;
#pragma unroll
                for (int jd = 0; jd < 4; jd++) {
                    int d = jd * 16 + lrow;
                    O[((size_t)(b_ * T_ + t)) * E_ + h_ * DH_ + d] = f2bf(accO[s][jd][r] * inv);
                }
            }
        }
    };

    run(qaA, qtA);
    run(qaB, qtB);
}

// ---------------- proj GEMM: 128x128 tile, BK=64, C^T orientation ----------------
__global__ __launch_bounds__(256) void gemm_proj(
    const ushort* __restrict__ Ob, const ushort* __restrict__ Wb,
    const float* __restrict__ bias, float* __restrict__ out)
{
    __shared__ ushort As[128 * 64];
    __shared__ ushort Bs[128 * 64];
    const int m0 = blockIdx.x * 128;
    const int n0 = blockIdx.y * 128;
    const int tid  = threadIdx.x;
    const int wave = tid >> 6, lane = tid & 63;
    const int lrow = lane & 15, quad = lane >> 4;
    const int srow8 = lane >> 3, scol8 = (lane & 7) * 8;

    const ushort* gA = Ob + (size_t)(m0 + wave * 8 + srow8) * 1024 + scol8;
    const ushort* gB = Wb + (size_t)(n0 + wave * 8 + srow8) * 1024 + scol8;

    const int mw = (wave >> 1) * 64, nw = (wave & 1) * 64;

    f32x4 acc[4][4];
#pragma unroll
    for (int i = 0; i < 4; i++)
#pragma unroll
        for (int j = 0; j < 4; j++) acc[i][j] = f32x4{0.f, 0.f, 0.f, 0.f};

    for (int k0 = 0; k0 < 1024; k0 += 64) {
        __syncthreads();
#pragma unroll
        for (int g = 0; g < 4; g++) {
            gload16(gA + (size_t)g * 32 * 1024 + k0, &As[(g * 32 + wave * 8) * 64]);
            gload16(gB + (size_t)g * 32 * 1024 + k0, &Bs[(g * 32 + wave * 8) * 64]);
        }
        __syncthreads();
#pragma unroll
        for (int ks = 0; ks < 2; ks++) {
            bf16x8 a[4], bfr[4];
#pragma unroll
            for (int i = 0; i < 4; i++)
                a[i] = *(const bf16x8*)&As[(mw + i * 16 + lrow) * 64 + ks * 32 + quad * 8];
#pragma unroll
            for (int j = 0; j < 4; j++)
                bfr[j] = *(const bf16x8*)&Bs[(nw + j * 16 + lrow) * 64 + ks * 32 + quad * 8];
#pragma unroll
            for (int i = 0; i < 4; i++)
#pragma unroll
                for (int j = 0; j < 4; j++)
                    acc[i][j] = __builtin_amdgcn_mfma_f32_16x16x32_bf16(bfr[j], a[i], acc[i][j], 0, 0, 0);
        }
    }

#pragma unroll
    for (int j = 0; j < 4; j++) {
        int n = n0 + nw + j * 16 + quad * 4;
        float4 bv = *(const float4*)&bias[n];
#pragma unroll
        for (int i = 0; i < 4; i++) {
            int m = m0 + mw + i * 16 + lrow;
            float4 o;
            o.x = acc[i][j][0] + bv.x;
            o.y = acc[i][j][1] + bv.y;
            o.z = acc[i][j][2] + bv.z;
            o.w = acc[i][j][3] + bv.w;
            *(float4*)&out[(size_t)m * 1024 + n] = o;
        }
    }
}

extern "C" void kernel_launch(void* const* d_in, const int* in_sizes, int n_in,
                              void* d_out, int out_size, void* d_ws, size_t ws_size,
                              hipStream_t stream) {
    const float* x      = (const float*)d_in[0];
    const float* w_qkv  = (const float*)d_in[1];
    const float* b_qkv  = (const float*)d_in[2];
    const float* w_proj = (const float*)d_in[3];
    const float* b_proj = (const float*)d_in[4];
    float* out = (float*)d_out;

    char* ws = (char*)d_ws;
    ushort* Xb     = (ushort*)ws; ws += (size_t)B_ * T_ * E_ * 2;
    ushort* Wqkvb  = (ushort*)ws; ws += (size_t)3 * E_ * E_ * 2;
    ushort* Wprojb = (ushort*)ws; ws += (size_t)E_ * E_ * 2;
    ushort* Qb     = (ushort*)ws; ws += (size_t)B_ * H_ * T_ * DH_ * 2;
    ushort* Kb     = (ushort*)ws; ws += (size_t)B_ * H_ * T_ * DH_ * 2;
    ushort* Vtb    = (ushort*)ws; ws += (size_t)B_ * H_ * T_ * DH_ * 2;
    ushort* Ob     = (ushort*)ws; ws += (size_t)B_ * T_ * E_ * 2;

    int ntot = (B_ * T_ * E_ + 3 * E_ * E_ + E_ * E_) / 4;
    cvt_all<<<ntot / 256, 256, 0, stream>>>(x, w_qkv, w_proj, Xb, Wqkvb, Wprojb);

    gemm_qkv<<<dim3(64, 24), 256, 0, stream>>>(Xb, Wqkvb, b_qkv, Qb, Kb, Vtb);
    flash_attn<<<dim3(8, 64), 256, 0, stream>>>(Qb, Kb, Vtb, Ob);
    gemm_proj<<<dim3(64, 8), 256, 0, stream>>>(Ob, Wprojb, b_proj, out);
}

// Round 11
// 243.934 us; speedup vs baseline: 1.2958x; 1.0839x over previous
//
#include <hip/hip_runtime.h>
#include <hip/hip_bf16.h>

#define B_ 4
#define T_ 2048
#define E_ 1024
#define H_ 16
#define DH_ 64
#define QSCALE_ 0.18033688f   // 0.125 * log2(e): QK^T comes out in log2 domain

typedef __attribute__((ext_vector_type(8))) short bf16x8;
typedef __attribute__((ext_vector_type(4))) float f32x4;
typedef unsigned int u32;

__device__ inline ushort f2bf(float f) {
    union { float f; unsigned u; } v; v.f = f;
    unsigned r = (v.u + 0x7fffu + ((v.u >> 16) & 1u)) >> 16;
    return (ushort)r;
}

// pack two f32 -> two bf16 (truncation) in one v_perm_b32: a->low, b->high
__device__ inline u32 pack2bf(float a, float b) {
    union { float f; u32 u; } ua, ub; ua.f = a; ub.f = b;
    return __builtin_amdgcn_perm(ub.u, ua.u, 0x07060302);
}

__device__ inline void gload16(const ushort* g, ushort* l) {
    __builtin_amdgcn_global_load_lds((const __attribute__((address_space(1))) u32*)g,
                                     (__attribute__((address_space(3))) u32*)l, 16, 0, 0);
}

// ---------------- fused f32 -> bf16 convert ----------------
__global__ void cvt_all(const float* __restrict__ x, const float* __restrict__ wq,
                        const float* __restrict__ wp,
                        ushort* __restrict__ xo, ushort* __restrict__ wqo, ushort* __restrict__ wpo)
{
    const int NX = B_ * T_ * E_ / 4;
    const int NW = 3 * E_ * E_ / 4;
    int i = blockIdx.x * 256 + threadIdx.x;
    const float* s; ushort* d; int off;
    if (i < NX)            { s = x;  d = xo;  off = i; }
    else if (i < NX + NW)  { s = wq; d = wqo; off = i - NX; }
    else                   { s = wp; d = wpo; off = i - NX - NW; }
    float4 f = ((const float4*)s)[off];
    ushort4 u;
    u.x = f2bf(f.x); u.y = f2bf(f.y); u.z = f2bf(f.z); u.w = f2bf(f.w);
    ((ushort4*)d)[off] = u;
}

// ---------------- QKV GEMM: 128x128 tile, BK=64, XOR-swizzled LDS ----------------
// LDS layout: logical 16B unit u of row r stored at unit (u ^ (r&7)).
// Staging keeps global_load_lds linear-dst (source address permuted per lane);
// b128 frag reads then spread across all 32 banks (2-way max).
__global__ __launch_bounds__(256) void gemm_qkv(
    const ushort* __restrict__ Xb, const ushort* __restrict__ Wb,
    const float* __restrict__ bias,
    ushort* __restrict__ Q, ushort* __restrict__ K, ushort* __restrict__ Vt)
{
    __shared__ ushort As[128 * 64];
    __shared__ ushort Bs[128 * 64];
    const int m0 = blockIdx.x * 128;
    const int n0 = blockIdx.y * 128;
    const int kind = n0 >> 10;           // 0=Q 1=K 2=V (block-uniform)
    const int tid  = threadIdx.x;
    const int wave = tid >> 6, lane = tid & 63;
    const int lrow = lane & 15, quad = lane >> 4;
    const int srow8 = lane >> 3;
    const int scol8 = ((lane & 7) ^ srow8) * 8;   // XOR-swizzled source column

    const ushort* gA = Xb + (size_t)(m0 + wave * 8 + srow8) * 1024 + scol8;
    const ushort* gB = Wb + (size_t)(n0 + wave * 8 + srow8) * 1024 + scol8;

    const int mw = (wave >> 1) * 64, nw = (wave & 1) * 64;
    const int rsw = (lrow & 7);          // row&7 for frag reads

    f32x4 acc[4][4];
#pragma unroll
    for (int i = 0; i < 4; i++)
#pragma unroll
        for (int j = 0; j < 4; j++) acc[i][j] = f32x4{0.f, 0.f, 0.f, 0.f};

    const int b = m0 >> 11;   // batch (block never straddles a 2048 boundary)
    const bool ct = (kind != 2);

    for (int k0 = 0; k0 < 1024; k0 += 64) {
        __syncthreads();
#pragma unroll
        for (int g = 0; g < 4; g++) {
            gload16(gA + (size_t)g * 32 * 1024 + k0, &As[(g * 32 + wave * 8) * 64]);
            gload16(gB + (size_t)g * 32 * 1024 + k0, &Bs[(g * 32 + wave * 8) * 64]);
        }
        __syncthreads();
#pragma unroll
        for (int ks = 0; ks < 2; ks++) {
            const int usw = ((ks * 4 + quad) ^ rsw) * 8;   // swizzled unit offset
            bf16x8 a[4], bfr[4];
#pragma unroll
            for (int i = 0; i < 4; i++)
                a[i] = *(const bf16x8*)&As[(mw + i * 16 + lrow) * 64 + usw];
#pragma unroll
            for (int j = 0; j < 4; j++)
                bfr[j] = *(const bf16x8*)&Bs[(nw + j * 16 + lrow) * 64 + usw];
            if (ct) {
#pragma unroll
                for (int i = 0; i < 4; i++)
#pragma unroll
                    for (int j = 0; j < 4; j++)
                        acc[i][j] = __builtin_amdgcn_mfma_f32_16x16x32_bf16(bfr[j], a[i], acc[i][j], 0, 0, 0);
            } else {
#pragma unroll
                for (int i = 0; i < 4; i++)
#pragma unroll
                    for (int j = 0; j < 4; j++)
                        acc[i][j] = __builtin_amdgcn_mfma_f32_16x16x32_bf16(a[i], bfr[j], acc[i][j], 0, 0, 0);
            }
        }
    }

    if (ct) {
        // C^T: lane holds m = mw+i*16+lrow, n = nw+j*16+quad*4+r -> ushort4 along d
        ushort* dst = (kind == 0) ? Q : K;
        const float scale = (kind == 0) ? QSCALE_ : 1.f;
#pragma unroll
        for (int j = 0; j < 4; j++) {
            int nq = (n0 & 1023) + nw + j * 16 + quad * 4;
            int h = nq >> 6, d = nq & 63;
            float4 bv = *(const float4*)&bias[n0 + nw + j * 16 + quad * 4];
            size_t bh = (size_t)(b * H_ + h);
#pragma unroll
            for (int i = 0; i < 4; i++) {
                int t = (m0 + mw + i * 16 + lrow) & 2047;   // batch-local!
                ushort4 o;
                o.x = f2bf((acc[i][j][0] + bv.x) * scale);
                o.y = f2bf((acc[i][j][1] + bv.y) * scale);
                o.z = f2bf((acc[i][j][2] + bv.z) * scale);
                o.w = f2bf((acc[i][j][3] + bv.w) * scale);
                *(ushort4*)&dst[(bh * T_ + t) * DH_ + d] = o;
            }
        }
    } else {
        // normal: lane holds n = nw+j*16+lrow, t = mw+i*16+quad*4+r -> ushort4 along t
#pragma unroll
        for (int j = 0; j < 4; j++) {
            int nv = (n0 & 1023) + nw + j * 16 + lrow;
            int h = nv >> 6, d = nv & 63;
            float bv = bias[n0 + nw + j * 16 + lrow];
            size_t bh = (size_t)(b * H_ + h);
#pragma unroll
            for (int i = 0; i < 4; i++) {
                int t = (m0 + mw + i * 16 + quad * 4) & 2047;   // batch-local!
                ushort4 o;
                o.x = f2bf(acc[i][j][0] + bv);
                o.y = f2bf(acc[i][j][1] + bv);
                o.z = f2bf(acc[i][j][2] + bv);
                o.w = f2bf(acc[i][j][3] + bv);
                *(ushort4*)&Vt[(bh * DH_ + d) * T_ + t] = o;
            }
        }
    }
}

// ---------------- Flash attention: paired q-tiles (R8-proven version) ----------------
#define LDT_ 76

__global__ __launch_bounds__(256) void flash_attn(
    const ushort* __restrict__ Q, const ushort* __restrict__ K,
    const ushort* __restrict__ Vg,   // [bh][DH][T]
    ushort* __restrict__ O)
{
    __shared__ ushort Ks[64 * LDT_];
    __shared__ ushort Vt[64 * LDT_];
    __shared__ ushort Ps[128 * LDT_];   // doubles as Q staging

    const int qtA = 15 - blockIdx.x;     // long tile
    const int qtB = blockIdx.x;          // short tile
    const int bh = blockIdx.y;
    const int tid  = threadIdx.x;
    const int wave = tid >> 6, lane = tid & 63;
    const int lrow = lane & 15, quad = lane >> 4;
    const int sr = tid >> 2, sc = (tid & 3) * 16;   // K/V staging coords

    const ushort* Qbh = Q  + (size_t)bh * T_ * DH_;
    const ushort* Kbh = K  + (size_t)bh * T_ * DH_;
    const ushort* Vbh = Vg + (size_t)bh * DH_ * T_;
    const int b_ = bh >> 4, h_ = bh & 15;

    auto stageQ = [&](int qt, bf16x8 qa[2][2]) {
        int qr = tid >> 1, qc = (tid & 1) * 32;
        const ushort* src = &Qbh[(size_t)(qt * 128 + qr) * DH_ + qc];
#pragma unroll
        for (int i = 0; i < 4; i++)
            *(int4*)&Ps[qr * LDT_ + qc + 8 * i] = *(const int4*)&src[8 * i];
        __syncthreads();
#pragma unroll
        for (int s = 0; s < 2; s++)
#pragma unroll
            for (int h = 0; h < 2; h++)
                qa[s][h] = *(const bf16x8*)&Ps[(s * 64 + wave * 16 + lrow) * LDT_ + h * 32 + quad * 8];
    };

    bf16x8 qaA[2][2], qaB[2][2];
    stageQ(qtA, qaA);
    __syncthreads();
    stageQ(qtB, qaB);

    auto run = [&](const bf16x8 (&qa)[2][2], int qt) {
        const int lastkt = 2 * qt + 1;

        int4 kr0 = *(const int4*)&Kbh[(size_t)sr * DH_ + sc];
        int4 kr1 = *(const int4*)&Kbh[(size_t)sr * DH_ + sc + 8];
        int4 vr0 = *(const int4*)&Vbh[(size_t)sr * T_ + sc];
        int4 vr1 = *(const int4*)&Vbh[(size_t)sr * T_ + sc + 8];

        float ls[2] = {0.f, 0.f};
        f32x4 accO[2][4];
#pragma unroll
        for (int s = 0; s < 2; s++)
#pragma unroll
            for (int j = 0; j < 4; j++) accO[s][j] = f32x4{0.f, 0.f, 0.f, 0.f};

        for (int kt = 0; kt <= lastkt; ++kt) {
            __syncthreads();
            *(int4*)&Ks[sr * LDT_ + sc]     = kr0;
            *(int4*)&Ks[sr * LDT_ + sc + 8] = kr1;
            *(int4*)&Vt[sr * LDT_ + sc]     = vr0;
            *(int4*)&Vt[sr * LDT_ + sc + 8] = vr1;
            __syncthreads();
            if (kt < lastkt) {
                kr0 = *(const int4*)&Kbh[(size_t)((kt + 1) * 64 + sr) * DH_ + sc];
                kr1 = *(const int4*)&Kbh[(size_t)((kt + 1) * 64 + sr) * DH_ + sc + 8];
                vr0 = *(const int4*)&Vbh[(size_t)sr * T_ + (kt + 1) * 64 + sc];
                vr1 = *(const int4*)&Vbh[(size_t)sr * T_ + (kt + 1) * 64 + sc + 8];
            }

            bf16x8 kb0[4], kb1[4];
#pragma unroll
            for (int j = 0; j < 4; j++) {
                kb0[j] = *(const bf16x8*)&Ks[(j * 16 + lrow) * LDT_ + quad * 8];
                kb1[j] = *(const bf16x8*)&Ks[(j * 16 + lrow) * LDT_ + 32 + quad * 8];
            }

            const bool do0 = (kt != lastkt);
#pragma unroll
            for (int s = 0; s < 2; s++) {
                if (s == 0 && !do0) continue;
                f32x4 st[4];
#pragma unroll
                for (int j = 0; j < 4; j++) {
                    f32x4 sj = f32x4{0.f, 0.f, 0.f, 0.f};
                    sj = __builtin_amdgcn_mfma_f32_16x16x32_bf16(kb0[j], qa[s][0], sj, 0, 0, 0);
                    sj = __builtin_amdgcn_mfma_f32_16x16x32_bf16(kb1[j], qa[s][1], sj, 0, 0, 0);
                    st[j] = sj;
                }
                if (kt == 2 * qt + s) {
                    const int qrow = qt * 128 + s * 64 + wave * 16 + lrow;
                    const int keyb = kt * 64 + quad * 4;
#pragma unroll
                    for (int j = 0; j < 4; j++)
#pragma unroll
                        for (int r = 0; r < 4; r++)
                            if (keyb + j * 16 + r > qrow) st[j][r] = -1e30f;
                }
                float lp = 0.f;
#pragma unroll
                for (int j = 0; j < 4; j++)
#pragma unroll
                    for (int r = 0; r < 4; r++) {
                        float p = __builtin_amdgcn_exp2f(st[j][r]);
                        st[j][r] = p;
                        lp += p;
                    }
                ls[s] += lp;
                ushort* prow = &Ps[(s * 64 + wave * 16 + lrow) * LDT_ + quad * 4];
#pragma unroll
                for (int j = 0; j < 4; j++) {
                    *(u32*)&prow[j * 16]     = pack2bf(st[j][0], st[j][1]);
                    *(u32*)&prow[j * 16 + 2] = pack2bf(st[j][2], st[j][3]);
                }
            }

            bf16x8 vb0[4], vb1[4];
#pragma unroll
            for (int j = 0; j < 4; j++) {
                vb0[j] = *(const bf16x8*)&Vt[(j * 16 + lrow) * LDT_ + quad * 8];
                vb1[j] = *(const bf16x8*)&Vt[(j * 16 + lrow) * LDT_ + 32 + quad * 8];
            }
#pragma unroll
            for (int s = 0; s < 2; s++) {
                if (s == 0 && !do0) continue;
                bf16x8 pa0 = *(const bf16x8*)&Ps[(s * 64 + wave * 16 + lrow) * LDT_ + quad * 8];
                bf16x8 pa1 = *(const bf16x8*)&Ps[(s * 64 + wave * 16 + lrow) * LDT_ + 32 + quad * 8];
#pragma unroll
                for (int jd = 0; jd < 4; jd++) {
                    accO[s][jd] = __builtin_amdgcn_mfma_f32_16x16x32_bf16(pa0, vb0[jd], accO[s][jd], 0, 0, 0);
                    accO[s][jd] = __builtin_amdgcn_mfma_f32_16x16x32_bf16(pa1, vb1[jd], accO[s][jd], 0, 0, 0);
                }
            }
        }

#pragma unroll
        for (int s = 0; s < 2; s++) {
            ls[s] += __shfl_xor(ls[s], 16, 64);
            ls[s] += __shfl_xor(ls[s], 32, 64);
        }
#pragma unroll
        for (int s = 0; s < 2; s++) {
#pragma unroll
            for (int r = 0; r < 4; r++) {
                float lv = __shfl(ls[s], quad * 4 + r, 64);
                float inv = 1.f / lv;
                int t = qt * 128 + s * 64 + wave * 16 + quad * 4 + r;
#pragma unroll
                for (int jd = 0; jd < 4; jd++) {
                    int d = jd * 16 + lrow;
                    O[((size_t)(b_ * T_ + t)) * E_ + h_ * DH_ + d] = f2bf(accO[s][jd][r] * inv);
                }
            }
        }
    };

    run(qaA, qtA);
    run(qaB, qtB);
}

// ---------------- proj GEMM: 128x128 tile, BK=64, XOR-swizzled, C^T stores ----------------
__global__ __launch_bounds__(256) void gemm_proj(
    const ushort* __restrict__ Ob, const ushort* __restrict__ Wb,
    const float* __restrict__ bias, float* __restrict__ out)
{
    __shared__ ushort As[128 * 64];
    __shared__ ushort Bs[128 * 64];
    const int m0 = blockIdx.x * 128;
    const int n0 = blockIdx.y * 128;
    const int tid  = threadIdx.x;
    const int wave = tid >> 6, lane = tid & 63;
    const int lrow = lane & 15, quad = lane >> 4;
    const int srow8 = lane >> 3;
    const int scol8 = ((lane & 7) ^ srow8) * 8;

    const ushort* gA = Ob + (size_t)(m0 + wave * 8 + srow8) * 1024 + scol8;
    const ushort* gB = Wb + (size_t)(n0 + wave * 8 + srow8) * 1024 + scol8;

    const int mw = (wave >> 1) * 64, nw = (wave & 1) * 64;
    const int rsw = (lrow & 7);

    f32x4 acc[4][4];
#pragma unroll
    for (int i = 0; i < 4; i++)
#pragma unroll
        for (int j = 0; j < 4; j++) acc[i][j] = f32x4{0.f, 0.f, 0.f, 0.f};

    for (int k0 = 0; k0 < 1024; k0 += 64) {
        __syncthreads();
#pragma unroll
        for (int g = 0; g < 4; g++) {
            gload16(gA + (size_t)g * 32 * 1024 + k0, &As[(g * 32 + wave * 8) * 64]);
            gload16(gB + (size_t)g * 32 * 1024 + k0, &Bs[(g * 32 + wave * 8) * 64]);
        }
        __syncthreads();
#pragma unroll
        for (int ks = 0; ks < 2; ks++) {
            const int usw = ((ks * 4 + quad) ^ rsw) * 8;
            bf16x8 a[4], bfr[4];
#pragma unroll
            for (int i = 0; i < 4; i++)
                a[i] = *(const bf16x8*)&As[(mw + i * 16 + lrow) * 64 + usw];
#pragma unroll
            for (int j = 0; j < 4; j++)
                bfr[j] = *(const bf16x8*)&Bs[(nw + j * 16 + lrow) * 64 + usw];
#pragma unroll
            for (int i = 0; i < 4; i++)
#pragma unroll
                for (int j = 0; j < 4; j++)
                    acc[i][j] = __builtin_amdgcn_mfma_f32_16x16x32_bf16(bfr[j], a[i], acc[i][j], 0, 0, 0);
        }
    }

#pragma unroll
    for (int j = 0; j < 4; j++) {
        int n = n0 + nw + j * 16 + quad * 4;
        float4 bv = *(const float4*)&bias[n];
#pragma unroll
        for (int i = 0; i < 4; i++) {
            int m = m0 + mw + i * 16 + lrow;
            float4 o;
            o.x = acc[i][j][0] + bv.x;
            o.y = acc[i][j][1] + bv.y;
            o.z = acc[i][j][2] + bv.z;
            o.w = acc[i][j][3] + bv.w;
            *(float4*)&out[(size_t)m * 1024 + n] = o;
        }
    }
}

extern "C" void kernel_launch(void* const* d_in, const int* in_sizes, int n_in,
                              void* d_out, int out_size, void* d_ws, size_t ws_size,
                              hipStream_t stream) {
    const float* x      = (const float*)d_in[0];
    const float* w_qkv  = (const float*)d_in[1];
    const float* b_qkv  = (const float*)d_in[2];
    const float* w_proj = (const float*)d_in[3];
    const float* b_proj = (const float*)d_in[4];
    float* out = (float*)d_out;

    char* ws = (char*)d_ws;
    ushort* Xb     = (ushort*)ws; ws += (size_t)B_ * T_ * E_ * 2;
    ushort* Wqkvb  = (ushort*)ws; ws += (size_t)3 * E_ * E_ * 2;
    ushort* Wprojb = (ushort*)ws; ws += (size_t)E_ * E_ * 2;
    ushort* Qb     = (ushort*)ws; ws += (size_t)B_ * H_ * T_ * DH_ * 2;
    ushort* Kb     = (ushort*)ws; ws += (size_t)B_ * H_ * T_ * DH_ * 2;
    ushort* Vtb    = (ushort*)ws; ws += (size_t)B_ * H_ * T_ * DH_ * 2;
    ushort* Ob     = (ushort*)ws; ws += (size_t)B_ * T_ * E_ * 2;

    int ntot = (B_ * T_ * E_ + 3 * E_ * E_ + E_ * E_) / 4;
    cvt_all<<<ntot / 256, 256, 0, stream>>>(x, w_qkv, w_proj, Xb, Wqkvb, Wprojb);

    gemm_qkv<<<dim3(64, 24), 256, 0, stream>>>(Xb, Wqkvb, b_qkv, Qb, Kb, Vtb);
    flash_attn<<<dim3(8, 64), 256, 0, stream>>>(Qb, Kb, Vtb, Ob);
    gemm_proj<<<dim3(64, 8), 256, 0, stream>>>(Ob, Wprojb, b_proj, out);
}